// Round 10
// baseline (333.330 us; speedup 1.0000x reference)
//
#include <hip/hip_runtime.h>
#include <hip/hip_bf16.h>

// RSFConv2d round 10: single-pass persistent-column MFMA conv.
//  - 1024 blocks (8n x 16xt x 8yseg, XCD-bijective y-fastest). Each block
//    walks 64 output rows in 8 steps of 8 rows.
//  - LDS ring: 18 rows x 34 px x 64B (bf16 32ch/px, col-swizzled slots).
//    slot(gy) = (gy+1)%18; stage(t+1) writes the 8 slots step t never reads.
//  - Per step: issue fp32 loads (t+1) -> 72 MFMAs (A-frags loop-invariant in
//    regs, B ds_reads deduped via m=f+dy) -> cvt+ds_write (t+1) -> barrier
//    (stage latency hidden under compute; no convoy drain) -> nt stores.
//  - Fixes R5's pipeline failure (A reloaded per phase) and removes R9's
//    110us xform pass. Roofline: 546MB / 6.3TB/s ~ 87us + overheads.

typedef __attribute__((ext_vector_type(8))) short bf16x8;
typedef __attribute__((ext_vector_type(16))) float f32x16;
typedef __attribute__((ext_vector_type(4))) unsigned int u32x4;
typedef __attribute__((ext_vector_type(4))) float f32x4v;

__device__ __forceinline__ unsigned short f2bf(float f) {
    unsigned u = __float_as_uint(f);
    u = u + 0x7fffu + ((u >> 16) & 1u);  // RNE
    return (unsigned short)(u >> 16);
}
__device__ __forceinline__ float bf2f(unsigned short b) {
    return __uint_as_float(((unsigned)b) << 16);
}

// ---------------- kernel synthesis: one thread per (o,i) pair ----------------
__global__ __launch_bounds__(256) void prep_kernel(const float* __restrict__ fw,
                                                   unsigned short* __restrict__ wbuf)
{
    int gid = blockIdx.x * blockDim.x + threadIdx.x;
    if (gid >= 32 * 32) return;
    int o = gid >> 5;
    int i = gid & 31;

    const float* f = fw + (size_t)gid * 12;
    float re[3][2], im[3][2];
#pragma unroll
    for (int ky = 0; ky < 3; ++ky)
#pragma unroll
        for (int kx = 0; kx < 2; ++kx) {
            re[ky][kx] = f[(ky * 2 + kx) * 2 + 0];
            im[ky][kx] = f[(ky * 2 + kx) * 2 + 1];
        }

    const float c3[3] = {1.f, -0.5f, -0.5f};
    const float s3[3] = {0.f, 0.86602540378443864676f, -0.86602540378443864676f};

    float base[3][3];
#pragma unroll
    for (int y = 0; y < 3; ++y)
#pragma unroll
        for (int x = 0; x < 3; ++x) {
            float sum = 0.f;
#pragma unroll
            for (int ky = 0; ky < 3; ++ky)
#pragma unroll
                for (int kx = 0; kx < 3; ++kx) {
                    float rf, mf;
                    if (kx < 2) {
                        rf = re[ky][kx];
                        mf = im[ky][kx];
                    } else {
                        int kys = (3 - ky) % 3;
                        rf = re[kys][1];
                        mf = -im[kys][1];
                    }
                    int m = (ky * y + kx * x) % 3;
                    sum += rf * c3[m] - mf * s3[m];
                }
            base[y][x] = sum * (1.f / 9.f);
        }

    const float scales[4] = {1.f, 1.25f, 1.5625f, 1.953125f};
    const float coords[3] = {-2.f / 3.f, 0.f, 2.f / 3.f};

    float acc[3][3] = {{0.f, 0.f, 0.f}, {0.f, 0.f, 0.f}, {0.f, 0.f, 0.f}};

    for (int t = 0; t < 32; ++t) {
        int r = t >> 2, si = t & 3;
        float th = (float)r * 0.78539816339744830961f;
        float sc = scales[si];
        float c = cosf(th) * sc;
        float s = sinf(th) * sc;
#pragma unroll
        for (int p = 0; p < 3; ++p) {
#pragma unroll
            for (int q = 0; q < 3; ++q) {
                float gxo = coords[q], gyo = coords[p];
                float gx = c * gxo - s * gyo;
                float gy = s * gxo + c * gyo;
                float ix = ((gx + 1.f) * 3.f - 1.f) * 0.5f;
                float iy = ((gy + 1.f) * 3.f - 1.f) * 0.5f;
                float fx0 = floorf(ix), fy0 = floorf(iy);
                int x0 = (int)fx0, y0 = (int)fy0;
                int x1 = x0 + 1, y1 = y0 + 1;
                float wx1 = ix - fx0, wy1 = iy - fy0;
                float wx0 = 1.f - wx1, wy0 = 1.f - wy1;

                float v = 0.f;
                {
                    int yc = min(max(y0, 0), 2), xc = min(max(x0, 0), 2);
                    bool ok = (x0 >= 0) & (x0 < 3) & (y0 >= 0) & (y0 < 3);
                    v += (ok ? base[yc][xc] : 0.f) * (wy0 * wx0);
                }
                {
                    int yc = min(max(y0, 0), 2), xc = min(max(x1, 0), 2);
                    bool ok = (x1 >= 0) & (x1 < 3) & (y0 >= 0) & (y0 < 3);
                    v += (ok ? base[yc][xc] : 0.f) * (wy0 * wx1);
                }
                {
                    int yc = min(max(y1, 0), 2), xc = min(max(x0, 0), 2);
                    bool ok = (x0 >= 0) & (x0 < 3) & (y1 >= 0) & (y1 < 3);
                    v += (ok ? base[yc][xc] : 0.f) * (wy1 * wx0);
                }
                {
                    int yc = min(max(y1, 0), 2), xc = min(max(x1, 0), 2);
                    bool ok = (x1 >= 0) & (x1 < 3) & (y1 >= 0) & (y1 < 3);
                    v += (ok ? base[yc][xc] : 0.f) * (wy1 * wx1);
                }
                acc[p][q] += v;
            }
        }
    }

    // wbuf[(tap*2+hl)*1024 + o*32 + i]: A rows = o, k = i.
#pragma unroll
    for (int p = 0; p < 3; ++p)
#pragma unroll
        for (int q = 0; q < 3; ++q) {
            int t = p * 3 + q;
            float w = acc[p][q] * (1.f / 32.f);
            unsigned short wh = f2bf(w);
            unsigned short wl = f2bf(w - bf2f(wh));
            size_t b = (size_t)(t * 2) * 1024 + o * 32 + i;
            wbuf[b] = wh;
            wbuf[b + 1024] = wl;
        }
}

// ---------------- persistent column conv ----------------
#define RING 18
#define ROWB 2176  // 34 px-slots x 64 B (px 0..31 main, 32 left halo, 33 right)

__device__ __forceinline__ void stage_main_write(char* ring, const float v[8][4],
                                                 int gy, int q, int c)
{
    unsigned base = ((unsigned)(gy + 1) % 18u) * ROWB;
#pragma unroll
    for (int j = 0; j < 4; ++j) {
        u32x4 d;
#pragma unroll
        for (int p = 0; p < 4; ++p)
            d[p] = (unsigned)f2bf(v[2 * p][j]) | ((unsigned)f2bf(v[2 * p + 1][j]) << 16);
        int px = (q << 2) + j;
        *(u32x4*)(ring + base + px * 64 + ((((px >> 1) & 3) ^ c) << 4)) = d;
    }
}

__device__ __forceinline__ void stage_halo_write(char* ring, const float v[8],
                                                 int gy, int side, int c)
{
    unsigned base = ((unsigned)(gy + 1) % 18u) * ROWB;
    u32x4 d;
#pragma unroll
    for (int p = 0; p < 4; ++p)
        d[p] = (unsigned)f2bf(v[2 * p]) | ((unsigned)f2bf(v[2 * p + 1]) << 16);
    int px = 32 + side;  // (px>>1)&3 == 0 for px 32/33
    *(u32x4*)(ring + base + px * 64 + (c << 4)) = d;
}

__global__ __launch_bounds__(256, 2) void conv_col(const float* __restrict__ x,
                                                   const unsigned short* __restrict__ wbuf,
                                                   float* __restrict__ out)
{
    __shared__ u32x4 ring4[RING * ROWB / 16];  // 39168 B
    char* ring = (char*)ring4;

    // 1024 blocks: XCD k = image k (lin&7); within: y-fastest 8yseg x 16xt
    const int lin = blockIdx.x;
    const int n = lin & 7;
    const int idx = lin >> 3;
    const int yseg = idx & 7;
    const int xt = idx >> 3;
    const int x0t = xt * 32;
    const int Y0 = yseg * 64;

    const int tid = threadIdx.x;
    const int lane = tid & 63;
    const int wv = tid >> 6;
    const int pxl = lane & 31;
    const int kh = lane >> 5;

    const float* xn = x + ((size_t)n << 23);

    // ---- A fragments, loop-invariant (36 x bf16x8 = 144 VGPR) ----
    bf16x8 A[3][3][2][2];
#pragma unroll
    for (int dy = 0; dy < 3; ++dy)
#pragma unroll
        for (int dx = 0; dx < 3; ++dx)
#pragma unroll
            for (int hl = 0; hl < 2; ++hl)
#pragma unroll
                for (int ks = 0; ks < 2; ++ks)
                    A[dy][dx][hl][ks] = *(const bf16x8*)(
                        wbuf + (size_t)(((dy * 3 + dx) * 2 + hl)) * 1024 +
                        pxl * 32 + ks * 16 + kh * 8);

    // ---- per-lane read column offsets (with halo remap) ----
    int coff[3];
#pragma unroll
    for (int dx = 0; dx < 3; ++dx) {
        int v = dx + pxl - 1;
        int pl = (v < 0) ? 32 : ((v == 32) ? 33 : v);
        coff[dx] = pl * 64 + ((((pl >> 1) & 3) ^ kh) << 4);
    }

    // ---- ring slots for compute rows, m = f+dy ----
    int sl[4];
#pragma unroll
    for (int m = 0; m < 4; ++m) sl[m] = (int)((unsigned)(Y0 + 2 * wv + m) % 18u);

    // ---- prologue: stage rows Y0-1 .. Y0+8 ----
    for (int pu = tid; pu < 320; pu += 256) {
        int row = pu >> 5, q = (pu >> 2) & 7, c = pu & 3;
        int gy = Y0 - 1 + row;
        bool ok = (unsigned)gy < 512u;
        int gyc = ok ? gy : 0;
        const float* src = xn + (((size_t)(c * 8)) << 18) + (gyc << 9) + x0t + (q << 2);
        float v[8][4];
#pragma unroll
        for (int cc = 0; cc < 8; ++cc) {
            f32x4v ld = *(const f32x4v*)(src + ((size_t)cc << 18));
#pragma unroll
            for (int j = 0; j < 4; ++j) v[cc][j] = ok ? ld[j] : 0.f;
        }
        stage_main_write(ring, v, gy, q, c);
    }
    if (tid < 80) {
        int row = tid >> 3, side = (tid >> 2) & 1, c = tid & 3;
        int gy = Y0 - 1 + row;
        int gx = side ? x0t + 32 : x0t - 1;
        bool ok = ((unsigned)gy < 512u) & ((unsigned)gx < 512u);
        int gyc = ok ? gy : 0, gxc = ok ? gx : 0;
        const float* src = xn + (((size_t)(c * 8)) << 18) + (gyc << 9) + gxc;
        float v[8];
#pragma unroll
        for (int cc = 0; cc < 8; ++cc) v[cc] = ok ? src[(size_t)cc << 18] : 0.f;
        stage_halo_write(ring, v, gy, side, c);
    }
    __syncthreads();

    // ---- 8 steps of 8 output rows ----
#pragma unroll 1
    for (int t = 0; t < 8; ++t) {
        const int R = Y0 + (t << 3);
        const bool st = (t < 7);

        // issue stage loads for step t+1 (latency hides under compute)
        float mv[8][4];
        float hv[8];
        int sgy = 0, sq = 0, sc = 0, hgy = 0, hside = 0, hc = 0;
        if (st) {
            sq = (tid >> 2) & 7;
            sc = tid & 3;
            sgy = R + 9 + (tid >> 5);
            bool ok = (unsigned)sgy < 512u;
            int gyc = ok ? sgy : 0;
            const float* src = xn + (((size_t)(sc * 8)) << 18) + (gyc << 9) + x0t + (sq << 2);
#pragma unroll
            for (int cc = 0; cc < 8; ++cc) {
                f32x4v ld = *(const f32x4v*)(src + ((size_t)cc << 18));
#pragma unroll
                for (int j = 0; j < 4; ++j) mv[cc][j] = ok ? ld[j] : 0.f;
            }
            if (tid < 64) {
                hside = (tid >> 2) & 1;
                hc = tid & 3;
                hgy = R + 9 + (tid >> 3);
                int hgx = hside ? x0t + 32 : x0t - 1;
                bool hok = ((unsigned)hgy < 512u) & ((unsigned)hgx < 512u);
                int gyc = hok ? hgy : 0, gxc = hok ? hgx : 0;
                const float* hsrc = xn + (((size_t)(hc * 8)) << 18) + (gyc << 9) + gxc;
#pragma unroll
                for (int cc = 0; cc < 8; ++cc) hv[cc] = hok ? hsrc[(size_t)cc << 18] : 0.f;
            }
        }

        // compute: 24 deduped B-reads, 72 MFMAs
        f32x16 acc[2];
#pragma unroll
        for (int f = 0; f < 2; ++f)
#pragma unroll
            for (int r = 0; r < 16; ++r) acc[f][r] = 0.f;

#pragma unroll
        for (int m = 0; m < 4; ++m) {
            const unsigned base = (unsigned)sl[m] * ROWB;
            bf16x8 b[3][2];
#pragma unroll
            for (int dx = 0; dx < 3; ++dx)
#pragma unroll
                for (int ks = 0; ks < 2; ++ks)
                    b[dx][ks] = *(const bf16x8*)(ring + base +
                                                 (unsigned)(coff[dx] ^ (ks << 5)));
#pragma unroll
            for (int f = 0; f < 2; ++f) {
                const int dy = m - f;
                if (dy >= 0 && dy < 3) {
#pragma unroll
                    for (int dx = 0; dx < 3; ++dx)
#pragma unroll
                        for (int ks = 0; ks < 2; ++ks) {
                            acc[f] = __builtin_amdgcn_mfma_f32_32x32x16_bf16(
                                A[dy][dx][0][ks], b[dx][ks], acc[f], 0, 0, 0);
                            acc[f] = __builtin_amdgcn_mfma_f32_32x32x16_bf16(
                                A[dy][dx][1][ks], b[dx][ks], acc[f], 0, 0, 0);
                        }
                }
            }
        }

        // convert + LDS writes for step t+1 (slots disjoint from step t reads)
        if (st) {
            stage_main_write(ring, mv, sgy, sq, sc);
            if (tid < 64) stage_halo_write(ring, hv, hgy, hside, hc);
        }
        __syncthreads();

        // stores (drain at NEXT step's barrier -> off critical path)
#pragma unroll
        for (int f = 0; f < 2; ++f) {
            int gy = R + (wv << 1) + f;
#pragma unroll
            for (int reg = 0; reg < 16; ++reg) {
                int o = (reg & 3) + 8 * (reg >> 2) + 4 * kh;
                size_t oidx = ((size_t)(n * 32 + o) << 18) + ((size_t)gy << 9) + x0t + pxl;
                __builtin_nontemporal_store(acc[f][reg], &out[oidx]);
            }
        }

        // advance ring slots by 8 mod 18
#pragma unroll
        for (int m = 0; m < 4; ++m) {
            sl[m] += 8;
            if (sl[m] >= 18) sl[m] -= 18;
        }
    }
}

extern "C" void kernel_launch(void* const* d_in, const int* in_sizes, int n_in,
                              void* d_out, int out_size, void* d_ws, size_t ws_size,
                              hipStream_t stream) {
    const float* x = (const float*)d_in[0];
    const float* fw = (const float*)d_in[1];
    float* out = (float*)d_out;
    unsigned short* wbuf = (unsigned short*)d_ws;  // 18*1024 bf16 = 36864 B

    prep_kernel<<<dim3(4), 256, 0, stream>>>(fw, wbuf);
    conv_col<<<dim3(1024), 256, 0, stream>>>(x, wbuf, out);
}

// Round 11
// 231.454 us; speedup vs baseline: 1.4402x; 1.4402x over previous
//
#include <hip/hip_runtime.h>
#include <hip/hip_bf16.h>

// RSFConv2d round 11: 32x32x16 MFMA implicit GEMM, 8x32 tile (R8 structure).
//  vs R8: (1) __launch_bounds__(256,4) -> 128-VGPR budget. R4-R9 all compiled
//         at 40-44 VGPR, which forces the compiler to SERIALIZE staging
//         (load unit -> drain -> cvt -> write -> next unit): each block pays
//         ~2 full HBM latencies; all pipes measured <16% busy.
//         (2) two-phase stage: issue ALL loads (unit0 + unit1, ~72 VGPR dest)
//         back-to-back, then convert+ds_write. Keeps ~16KB/wave in flight.
//  R10 post-mortem: persistent-column design needed ~220 live regs -> scratch
//  spills (FETCH 686MB = 2.2x ideal). This keeps live state <= ~110 regs.
//  Compute/epilogue identical to R4/R8 (proven 202-211us): A per-dy from
//  global, swizzled LDS b128 reads, full-line nontemporal stores, XCD-
//  bijective y-fastest block swizzle.

typedef __attribute__((ext_vector_type(8))) short bf16x8;
typedef __attribute__((ext_vector_type(16))) float f32x16;
typedef __attribute__((ext_vector_type(4))) unsigned int u32x4;
typedef __attribute__((ext_vector_type(4))) float f32x4v;

__device__ __forceinline__ unsigned short f2bf(float f) {
    unsigned u = __float_as_uint(f);
    u = u + 0x7fffu + ((u >> 16) & 1u);  // RNE
    return (unsigned short)(u >> 16);
}
__device__ __forceinline__ float bf2f(unsigned short b) {
    return __uint_as_float(((unsigned)b) << 16);
}

// ---------------- kernel synthesis: one thread per (o,i) pair ----------------
__global__ __launch_bounds__(256) void prep_kernel(const float* __restrict__ fw,
                                                   unsigned short* __restrict__ wbuf)
{
    int gid = blockIdx.x * blockDim.x + threadIdx.x;
    if (gid >= 32 * 32) return;
    int o = gid >> 5;
    int i = gid & 31;

    const float* f = fw + (size_t)gid * 12;
    float re[3][2], im[3][2];
#pragma unroll
    for (int ky = 0; ky < 3; ++ky)
#pragma unroll
        for (int kx = 0; kx < 2; ++kx) {
            re[ky][kx] = f[(ky * 2 + kx) * 2 + 0];
            im[ky][kx] = f[(ky * 2 + kx) * 2 + 1];
        }

    const float c3[3] = {1.f, -0.5f, -0.5f};
    const float s3[3] = {0.f, 0.86602540378443864676f, -0.86602540378443864676f};

    float base[3][3];
#pragma unroll
    for (int y = 0; y < 3; ++y)
#pragma unroll
        for (int x = 0; x < 3; ++x) {
            float sum = 0.f;
#pragma unroll
            for (int ky = 0; ky < 3; ++ky)
#pragma unroll
                for (int kx = 0; kx < 3; ++kx) {
                    float rf, mf;
                    if (kx < 2) {
                        rf = re[ky][kx];
                        mf = im[ky][kx];
                    } else {
                        int kys = (3 - ky) % 3;
                        rf = re[kys][1];
                        mf = -im[kys][1];
                    }
                    int m = (ky * y + kx * x) % 3;
                    sum += rf * c3[m] - mf * s3[m];
                }
            base[y][x] = sum * (1.f / 9.f);
        }

    const float scales[4] = {1.f, 1.25f, 1.5625f, 1.953125f};
    const float coords[3] = {-2.f / 3.f, 0.f, 2.f / 3.f};

    float acc[3][3] = {{0.f, 0.f, 0.f}, {0.f, 0.f, 0.f}, {0.f, 0.f, 0.f}};

    for (int t = 0; t < 32; ++t) {
        int r = t >> 2, si = t & 3;
        float th = (float)r * 0.78539816339744830961f;
        float sc = scales[si];
        float c = cosf(th) * sc;
        float s = sinf(th) * sc;
#pragma unroll
        for (int p = 0; p < 3; ++p) {
#pragma unroll
            for (int q = 0; q < 3; ++q) {
                float gxo = coords[q], gyo = coords[p];
                float gx = c * gxo - s * gyo;
                float gy = s * gxo + c * gyo;
                float ix = ((gx + 1.f) * 3.f - 1.f) * 0.5f;
                float iy = ((gy + 1.f) * 3.f - 1.f) * 0.5f;
                float fx0 = floorf(ix), fy0 = floorf(iy);
                int x0 = (int)fx0, y0 = (int)fy0;
                int x1 = x0 + 1, y1 = y0 + 1;
                float wx1 = ix - fx0, wy1 = iy - fy0;
                float wx0 = 1.f - wx1, wy0 = 1.f - wy1;

                float v = 0.f;
                {
                    int yc = min(max(y0, 0), 2), xc = min(max(x0, 0), 2);
                    bool ok = (x0 >= 0) & (x0 < 3) & (y0 >= 0) & (y0 < 3);
                    v += (ok ? base[yc][xc] : 0.f) * (wy0 * wx0);
                }
                {
                    int yc = min(max(y0, 0), 2), xc = min(max(x1, 0), 2);
                    bool ok = (x1 >= 0) & (x1 < 3) & (y0 >= 0) & (y0 < 3);
                    v += (ok ? base[yc][xc] : 0.f) * (wy0 * wx1);
                }
                {
                    int yc = min(max(y1, 0), 2), xc = min(max(x0, 0), 2);
                    bool ok = (x0 >= 0) & (x0 < 3) & (y1 >= 0) & (y1 < 3);
                    v += (ok ? base[yc][xc] : 0.f) * (wy1 * wx0);
                }
                {
                    int yc = min(max(y1, 0), 2), xc = min(max(x1, 0), 2);
                    bool ok = (x1 >= 0) & (x1 < 3) & (y1 >= 0) & (y1 < 3);
                    v += (ok ? base[yc][xc] : 0.f) * (wy1 * wx1);
                }
                acc[p][q] += v;
            }
        }
    }

    // wbuf[(tap*2+hl)*1024 + o*32 + i]: A rows = o, k = i.
#pragma unroll
    for (int p = 0; p < 3; ++p)
#pragma unroll
        for (int q = 0; q < 3; ++q) {
            int t = p * 3 + q;
            float w = acc[p][q] * (1.f / 32.f);
            unsigned short wh = f2bf(w);
            unsigned short wl = f2bf(w - bf2f(wh));
            size_t b = (size_t)(t * 2) * 1024 + o * 32 + i;
            wbuf[b] = wh;
            wbuf[b + 1024] = wl;
        }
}

// ---------------- conv: 8x32 tile, 4 waves, 32x32x16 MFMA ----------------
#define TLH 8
#define TLW 32
#define LCOLS 34
#define NPX 340  // 10*34 halo pixels, 64 B each (32 ch bf16)

// read-conflict-free bank swizzle: any 8 consecutive px cover all 8 16B phases
__device__ __forceinline__ unsigned lds_byte(int px, int c) {
    return ((unsigned)px << 6) + ((((unsigned)(px >> 1) & 3u) ^ (unsigned)c) << 4);
}

__global__ __launch_bounds__(256, 4) void conv_mfma(const float* __restrict__ x,
                                                    const unsigned short* __restrict__ wbuf,
                                                    float* __restrict__ out)
{
    __shared__ unsigned slds[NPX * 16];  // 21760 B

    // flat grid 8192; bijective XCD swizzle, y-fastest (XCD k = image k)
    const int lin = blockIdx.x;
    const int s = (lin & 7) * 1024 + (lin >> 3);
    const int n = s >> 10;
    const int rem = s & 1023;
    const int y0t = (rem & 63) * TLH;
    const int x0t = (rem >> 6) * TLW;

    const int tid = threadIdx.x;
    const float* xn = x + ((size_t)n << 23);

    // ======== STAGE, phase 1: issue ALL loads (no dependent ops between) ====
    // main units: u = (row<<5)|(q<<2)|c : row 0..9, q 0..7 (x-quad), c 0..3
    // unit0 = tid (units 0..255); unit1 = 256+tid for tid<64 (units 256..319);
    // halo unit hu = tid-64 for 64<=tid<144 (80 units: row,side,c).
    const int row0 = tid >> 5, q0 = (tid >> 2) & 7, c0 = tid & 3;
    const int gy0 = y0t + row0 - 1;
    const bool ok0 = (unsigned)gy0 < 512u;
    const float* src0 = xn + (((size_t)(c0 * 8)) << 18) + ((ok0 ? gy0 : 0) << 9) +
                        x0t + (q0 << 2);
    f32x4v L0[8];
#pragma unroll
    for (int cc = 0; cc < 8; ++cc) L0[cc] = *(const f32x4v*)(src0 + ((size_t)cc << 18));

    const int kind2 = (tid < 64) ? 1 : (tid < 144 ? 2 : 0);
    f32x4v L1[8];
    float H1[8];
    int row1 = 0, q1 = 0, c1 = 0, hside = 0, hc = 0, hrow = 0;
    bool ok1 = false, okh = false;
    if (kind2 == 1) {
        const int u1 = 256 + tid;  // 256..319
        row1 = u1 >> 5; q1 = (u1 >> 2) & 7; c1 = u1 & 3;
        int gy = y0t + row1 - 1;
        ok1 = (unsigned)gy < 512u;
        const float* src = xn + (((size_t)(c1 * 8)) << 18) + ((ok1 ? gy : 0) << 9) +
                           x0t + (q1 << 2);
#pragma unroll
        for (int cc = 0; cc < 8; ++cc) L1[cc] = *(const f32x4v*)(src + ((size_t)cc << 18));
    } else if (kind2 == 2) {
        const int hu = tid - 64;  // 0..79
        hrow = hu >> 3; hside = (hu >> 2) & 1; hc = hu & 3;
        int gy = y0t + hrow - 1;
        int gx = x0t + (hside ? 32 : -1);
        okh = ((unsigned)gy < 512u) & ((unsigned)gx < 512u);
        const float* src = xn + (((size_t)(hc * 8)) << 18) +
                           ((okh ? gy : 0) << 9) + (okh ? gx : 0);
#pragma unroll
        for (int cc = 0; cc < 8; ++cc) H1[cc] = src[(size_t)cc << 18];
    }

    // ======== STAGE, phase 2: convert + LDS writes ========
    {
        const int px0 = row0 * LCOLS + 1 + (q0 << 2);
#pragma unroll
        for (int j = 0; j < 4; ++j) {
            u32x4 d;
#pragma unroll
            for (int p = 0; p < 4; ++p) {
                float a = ok0 ? L0[2 * p][j] : 0.f;
                float b = ok0 ? L0[2 * p + 1][j] : 0.f;
                d[p] = (unsigned)f2bf(a) | ((unsigned)f2bf(b) << 16);
            }
            *(u32x4*)((char*)slds + lds_byte(px0 + j, c0)) = d;
        }
    }
    if (kind2 == 1) {
        const int px0 = row1 * LCOLS + 1 + (q1 << 2);
#pragma unroll
        for (int j = 0; j < 4; ++j) {
            u32x4 d;
#pragma unroll
            for (int p = 0; p < 4; ++p) {
                float a = ok1 ? L1[2 * p][j] : 0.f;
                float b = ok1 ? L1[2 * p + 1][j] : 0.f;
                d[p] = (unsigned)f2bf(a) | ((unsigned)f2bf(b) << 16);
            }
            *(u32x4*)((char*)slds + lds_byte(px0 + j, c1)) = d;
        }
    } else if (kind2 == 2) {
        u32x4 d;
#pragma unroll
        for (int p = 0; p < 4; ++p) {
            float a = okh ? H1[2 * p] : 0.f;
            float b = okh ? H1[2 * p + 1] : 0.f;
            d[p] = (unsigned)f2bf(a) | ((unsigned)f2bf(b) << 16);
        }
        int px = hrow * LCOLS + (hside ? 33 : 0);
        *(u32x4*)((char*)slds + lds_byte(px, hc)) = d;
    }
    __syncthreads();

    // ======== MFMA: wave wv owns out rows {2wv, 2wv+1}, all 32 o ========
    const int lane = tid & 63;
    const int wv = tid >> 6;    // 0..3
    const int pxl = lane & 31;  // B col = pixel
    const int kh = lane >> 5;   // B k-half
    const int r0 = wv << 1;

    f32x16 acc[2];
#pragma unroll
    for (int f = 0; f < 2; ++f)
#pragma unroll
        for (int r = 0; r < 16; ++r) acc[f][r] = 0.f;

#pragma unroll 1
    for (int dy = 0; dy < 3; ++dy) {
        // A-frags for this dy: lane holds row o=pxl, k = kh*8 + j of K=16
        bf16x8 A[3][2][2];  // [dx][hl][kstep]
#pragma unroll
        for (int dx = 0; dx < 3; ++dx)
#pragma unroll
            for (int hl = 0; hl < 2; ++hl)
#pragma unroll
                for (int ks = 0; ks < 2; ++ks) {
                    int tap = dy * 3 + dx;
                    A[dx][hl][ks] = *(const bf16x8*)(wbuf + (size_t)(tap * 2 + hl) * 1024 +
                                                     pxl * 32 + ks * 16 + kh * 8);
                }
#pragma unroll
        for (int f = 0; f < 2; ++f) {
            int lrow = r0 + f + dy;  // LDS row (0 = global y0t-1)
#pragma unroll
            for (int dx = 0; dx < 3; ++dx) {
                int px = lrow * LCOLS + dx + pxl;
#pragma unroll
                for (int ks = 0; ks < 2; ++ks) {
                    bf16x8 b = *(const bf16x8*)((const char*)slds + lds_byte(px, ks * 2 + kh));
                    acc[f] = __builtin_amdgcn_mfma_f32_32x32x16_bf16(A[dx][0][ks], b, acc[f], 0, 0, 0);
                    acc[f] = __builtin_amdgcn_mfma_f32_32x32x16_bf16(A[dx][1][ks], b, acc[f], 0, 0, 0);
                }
            }
        }
    }

    // ---- epilogue: C/D col=lane&31 (px), row=(reg&3)+8*(reg>>2)+4*(lane>>5) (o)
#pragma unroll
    for (int f = 0; f < 2; ++f) {
        int gy = y0t + r0 + f;
#pragma unroll
        for (int reg = 0; reg < 16; ++reg) {
            int o = (reg & 3) + 8 * (reg >> 2) + 4 * kh;
            size_t idx = ((size_t)(n * 32 + o) << 18) + (size_t)(gy << 9) + x0t + pxl;
            __builtin_nontemporal_store(acc[f][reg], &out[idx]);
        }
    }
}

extern "C" void kernel_launch(void* const* d_in, const int* in_sizes, int n_in,
                              void* d_out, int out_size, void* d_ws, size_t ws_size,
                              hipStream_t stream) {
    const float* x = (const float*)d_in[0];
    const float* fw = (const float*)d_in[1];
    float* out = (float*)d_out;
    unsigned short* wbuf = (unsigned short*)d_ws;  // 18*1024 bf16 = 36864 B

    prep_kernel<<<dim3(4), 256, 0, stream>>>(fw, wbuf);
    conv_mfma<<<dim3(8192), 256, 0, stream>>>(x, wbuf, out);
}

// Round 13
// 190.924 us; speedup vs baseline: 1.7459x; 1.2123x over previous
//
#include <hip/hip_runtime.h>
#include <hip/hip_bf16.h>

// RSFConv2d round 13: persistent-column pipelined MFMA conv (R12 + px fix).
//  R12 NaN root cause: stage wrote main pixels at px 1..32 (R8 convention,
//  col0=left-halo) while reads used the R10 remap (main 0..31, halo 32/33):
//  px0 never written (stale LDS -> NaN), px32 double-written. Fix: stage
//  main at px = q*4+j (0..31); halos at 32 (left) / 33 (right). Reads match.
//  Structure unchanged from R12:
//  - 1024 blocks (8n x 16xt x 8yseg, XCD-bijective), 64 rows in 8 steps.
//  - double-buffered 10-row LDS bands (2x21.8KB), 2-row refetch overlap.
//  - SINGLE bf16 weight (18 A-frags, 72 VGPR, loaded once); 36 MFMA/step.
//  - per step: issue band t+1 loads -> sched_barrier(0) -> ds_read+MFMA from
//    BUF[t&1] -> cvt+ds_write BUF[(t+1)&1] -> nt stores -> one barrier.

typedef __attribute__((ext_vector_type(8))) short bf16x8;
typedef __attribute__((ext_vector_type(16))) float f32x16;
typedef __attribute__((ext_vector_type(4))) unsigned int u32x4;
typedef __attribute__((ext_vector_type(4))) float f32x4v;

__device__ __forceinline__ unsigned short f2bf(float f) {
    unsigned u = __float_as_uint(f);
    u = u + 0x7fffu + ((u >> 16) & 1u);  // RNE
    return (unsigned short)(u >> 16);
}
__device__ __forceinline__ float bf2f(unsigned short b) {
    return __uint_as_float(((unsigned)b) << 16);
}

// ---------------- kernel synthesis: one thread per (o,i) pair ----------------
__global__ __launch_bounds__(256) void prep_kernel(const float* __restrict__ fw,
                                                   unsigned short* __restrict__ wbuf)
{
    int gid = blockIdx.x * blockDim.x + threadIdx.x;
    if (gid >= 32 * 32) return;
    int o = gid >> 5;
    int i = gid & 31;

    const float* f = fw + (size_t)gid * 12;
    float re[3][2], im[3][2];
#pragma unroll
    for (int ky = 0; ky < 3; ++ky)
#pragma unroll
        for (int kx = 0; kx < 2; ++kx) {
            re[ky][kx] = f[(ky * 2 + kx) * 2 + 0];
            im[ky][kx] = f[(ky * 2 + kx) * 2 + 1];
        }

    const float c3[3] = {1.f, -0.5f, -0.5f};
    const float s3[3] = {0.f, 0.86602540378443864676f, -0.86602540378443864676f};

    float base[3][3];
#pragma unroll
    for (int y = 0; y < 3; ++y)
#pragma unroll
        for (int x = 0; x < 3; ++x) {
            float sum = 0.f;
#pragma unroll
            for (int ky = 0; ky < 3; ++ky)
#pragma unroll
                for (int kx = 0; kx < 3; ++kx) {
                    float rf, mf;
                    if (kx < 2) {
                        rf = re[ky][kx];
                        mf = im[ky][kx];
                    } else {
                        int kys = (3 - ky) % 3;
                        rf = re[kys][1];
                        mf = -im[kys][1];
                    }
                    int m = (ky * y + kx * x) % 3;
                    sum += rf * c3[m] - mf * s3[m];
                }
            base[y][x] = sum * (1.f / 9.f);
        }

    const float scales[4] = {1.f, 1.25f, 1.5625f, 1.953125f};
    const float coords[3] = {-2.f / 3.f, 0.f, 2.f / 3.f};

    float acc[3][3] = {{0.f, 0.f, 0.f}, {0.f, 0.f, 0.f}, {0.f, 0.f, 0.f}};

    for (int t = 0; t < 32; ++t) {
        int r = t >> 2, si = t & 3;
        float th = (float)r * 0.78539816339744830961f;
        float sc = scales[si];
        float c = cosf(th) * sc;
        float s = sinf(th) * sc;
#pragma unroll
        for (int p = 0; p < 3; ++p) {
#pragma unroll
            for (int q = 0; q < 3; ++q) {
                float gxo = coords[q], gyo = coords[p];
                float gx = c * gxo - s * gyo;
                float gy = s * gxo + c * gyo;
                float ix = ((gx + 1.f) * 3.f - 1.f) * 0.5f;
                float iy = ((gy + 1.f) * 3.f - 1.f) * 0.5f;
                float fx0 = floorf(ix), fy0 = floorf(iy);
                int x0 = (int)fx0, y0 = (int)fy0;
                int x1 = x0 + 1, y1 = y0 + 1;
                float wx1 = ix - fx0, wy1 = iy - fy0;
                float wx0 = 1.f - wx1, wy0 = 1.f - wy1;

                float v = 0.f;
                {
                    int yc = min(max(y0, 0), 2), xc = min(max(x0, 0), 2);
                    bool ok = (x0 >= 0) & (x0 < 3) & (y0 >= 0) & (y0 < 3);
                    v += (ok ? base[yc][xc] : 0.f) * (wy0 * wx0);
                }
                {
                    int yc = min(max(y0, 0), 2), xc = min(max(x1, 0), 2);
                    bool ok = (x1 >= 0) & (x1 < 3) & (y0 >= 0) & (y0 < 3);
                    v += (ok ? base[yc][xc] : 0.f) * (wy0 * wx1);
                }
                {
                    int yc = min(max(y1, 0), 2), xc = min(max(x0, 0), 2);
                    bool ok = (x0 >= 0) & (x0 < 3) & (y1 >= 0) & (y1 < 3);
                    v += (ok ? base[yc][xc] : 0.f) * (wy1 * wx0);
                }
                {
                    int yc = min(max(y1, 0), 2), xc = min(max(x1, 0), 2);
                    bool ok = (x1 >= 0) & (x1 < 3) & (y1 >= 0) & (y1 < 3);
                    v += (ok ? base[yc][xc] : 0.f) * (wy1 * wx1);
                }
                acc[p][q] += v;
            }
        }
    }

    // wbuf[(tap*2+hl)*1024 + o*32 + i]; conv uses hl=0 (wh) only.
#pragma unroll
    for (int p = 0; p < 3; ++p)
#pragma unroll
        for (int q = 0; q < 3; ++q) {
            int t = p * 3 + q;
            float w = acc[p][q] * (1.f / 32.f);
            unsigned short wh = f2bf(w);
            unsigned short wl = f2bf(w - bf2f(wh));
            size_t b = (size_t)(t * 2) * 1024 + o * 32 + i;
            wbuf[b] = wh;
            wbuf[b + 1024] = wl;
        }
}

// ---------------- persistent pipelined conv ----------------
#define ROWB 2176   // 34 px-slots x 64 B (px 0..31 main, 32=left halo, 33=right)
#define BUFB 21760  // 10 rows

// swizzle slot: any 8 consecutive px cover all 8 16B phases
__device__ __forceinline__ unsigned swz(int px, int c) {
    return ((unsigned)px << 6) + ((((unsigned)(px >> 1) & 3u) ^ (unsigned)c) << 4);
}

__global__ __launch_bounds__(256, 2) void conv_pipe(const float* __restrict__ x,
                                                    const unsigned short* __restrict__ wbuf,
                                                    float* __restrict__ out)
{
    __shared__ char lds[2 * BUFB];  // 43520 B

    const int lin = blockIdx.x;     // 1024 blocks: XCD k = image k
    const int n = lin & 7;
    const int idx = lin >> 3;
    const int xt = idx & 15;
    const int yseg = idx >> 4;
    const int x0t = xt * 32;
    const int Y0 = yseg * 64;

    const int tid = threadIdx.x;
    const int lane = tid & 63;
    const int wv = tid >> 6;
    const int pxl = lane & 31;
    const int kh = lane >> 5;

    const float* xn = x + ((size_t)n << 23);

    // ---- A fragments (wh only), loop-invariant: 18 x bf16x8 = 72 VGPR ----
    bf16x8 A[3][3][2];  // [dy][dx][ks]
#pragma unroll
    for (int dy = 0; dy < 3; ++dy)
#pragma unroll
        for (int dx = 0; dx < 3; ++dx)
#pragma unroll
            for (int ks = 0; ks < 2; ++ks)
                A[dy][dx][ks] = *(const bf16x8*)(
                    wbuf + (size_t)((dy * 3 + dx) * 2) * 1024 +
                    pxl * 32 + ks * 16 + kh * 8);

    // ---- per-lane read column offsets (main 0..31, left halo 32, right 33) ----
    int coff[3];
#pragma unroll
    for (int dx = 0; dx < 3; ++dx) {
        int v = dx + pxl - 1;
        int pl = (v < 0) ? 32 : ((v == 32) ? 33 : v);
        coff[dx] = (int)swz(pl, kh);
    }

    // ---- prologue: stage band 0 (gy = Y0-1 .. Y0+8) into BUF0 ----
    for (int u = tid; u < 400; u += 256) {
        if (u < 320) {
            int row = u >> 5, q = (u >> 2) & 7, c = u & 3;
            int gy = Y0 - 1 + row;
            bool ok = (unsigned)gy < 512u;
            const float* src = xn + (((size_t)(c * 8)) << 18) + ((ok ? gy : 0) << 9) +
                               x0t + (q << 2);
            float v[8][4];
#pragma unroll
            for (int cc = 0; cc < 8; ++cc) {
                f32x4v ld = *(const f32x4v*)(src + ((size_t)cc << 18));
#pragma unroll
                for (int j = 0; j < 4; ++j) v[cc][j] = ok ? ld[j] : 0.f;
            }
            int px0 = (q << 2);  // R13 FIX: main px 0..31 (was 1+q*4)
#pragma unroll
            for (int j = 0; j < 4; ++j) {
                u32x4 d;
#pragma unroll
                for (int p = 0; p < 4; ++p)
                    d[p] = (unsigned)f2bf(v[2 * p][j]) | ((unsigned)f2bf(v[2 * p + 1][j]) << 16);
                *(u32x4*)(lds + row * ROWB + swz(px0 + j, c)) = d;
            }
        } else {
            int hu = u - 320;
            int row = hu >> 3, side = (hu >> 2) & 1, c = hu & 3;
            int gy = Y0 - 1 + row;
            int gx = x0t + (side ? 32 : -1);
            bool ok = ((unsigned)gy < 512u) & ((unsigned)gx < 512u);
            const float* src = xn + (((size_t)(c * 8)) << 18) +
                               ((ok ? gy : 0) << 9) + (ok ? gx : 0);
            u32x4 d;
#pragma unroll
            for (int p = 0; p < 4; ++p) {
                float a = ok ? src[(size_t)(2 * p) << 18] : 0.f;
                float b = ok ? src[(size_t)(2 * p + 1) << 18] : 0.f;
                d[p] = (unsigned)f2bf(a) | ((unsigned)f2bf(b) << 16);
            }
            // left halo (side=0, gx=x0t-1) -> px 32; right (side=1) -> px 33
            *(u32x4*)(lds + row * ROWB + swz(32 + side, c)) = d;
        }
    }
    __syncthreads();

    // ---- 8 steps of 8 output rows ----
#pragma unroll 1
    for (int t = 0; t < 8; ++t) {
        const int R = Y0 + (t << 3);
        const bool st = (t < 7);
        const char* rbuf = lds + (t & 1) * BUFB;
        char* wlds = lds + ((t + 1) & 1) * BUFB;

        // -- issue loads for band t+1 (rows gy = R+7 .. R+16) --
        f32x4v L0[8], L1[8];
        float H[8];
        int r0s = 0, q0 = 0, c0 = 0, r1s = 0, q1 = 0, c1 = 0;
        int hr = 0, hside = 0, hc = 0;
        bool ok0 = false, ok1 = false, okh = false;
        const int kind = (tid < 64) ? 1 : (tid < 144 ? 2 : 0);
        if (st) {
            r0s = tid >> 5; q0 = (tid >> 2) & 7; c0 = tid & 3;
            int gy = R + 7 + r0s;
            ok0 = (unsigned)gy < 512u;
            const float* src = xn + (((size_t)(c0 * 8)) << 18) + ((ok0 ? gy : 0) << 9) +
                               x0t + (q0 << 2);
#pragma unroll
            for (int cc = 0; cc < 8; ++cc) L0[cc] = *(const f32x4v*)(src + ((size_t)cc << 18));
            if (kind == 1) {
                int u = 256 + tid;
                r1s = u >> 5; q1 = (u >> 2) & 7; c1 = u & 3;
                int gy1 = R + 7 + r1s;
                ok1 = (unsigned)gy1 < 512u;
                const float* s1 = xn + (((size_t)(c1 * 8)) << 18) + ((ok1 ? gy1 : 0) << 9) +
                                  x0t + (q1 << 2);
#pragma unroll
                for (int cc = 0; cc < 8; ++cc) L1[cc] = *(const f32x4v*)(s1 + ((size_t)cc << 18));
            } else if (kind == 2) {
                int hu = tid - 64;
                hr = hu >> 3; hside = (hu >> 2) & 1; hc = hu & 3;
                int gy1 = R + 7 + hr;
                int gx = x0t + (hside ? 32 : -1);
                okh = ((unsigned)gy1 < 512u) & ((unsigned)gx < 512u);
                const float* s1 = xn + (((size_t)(hc * 8)) << 18) +
                                  ((okh ? gy1 : 0) << 9) + (okh ? gx : 0);
#pragma unroll
                for (int cc = 0; cc < 8; ++cc) H[cc] = s1[(size_t)cc << 18];
            }
        }
        __builtin_amdgcn_sched_barrier(0);  // loads issue BEFORE compute

        // -- compute band t: out rows R+2wv+{0,1} --
        f32x16 acc[2];
#pragma unroll
        for (int f = 0; f < 2; ++f)
#pragma unroll
            for (int r = 0; r < 16; ++r) acc[f][r] = 0.f;

#pragma unroll
        for (int m = 0; m < 4; ++m) {
            const int rs = (wv << 1) + m;  // row slot 0..9
            bf16x8 b[3][2];
#pragma unroll
            for (int dx = 0; dx < 3; ++dx)
#pragma unroll
                for (int ks = 0; ks < 2; ++ks)
                    b[dx][ks] = *(const bf16x8*)(rbuf + rs * ROWB +
                                                 (unsigned)(coff[dx] ^ (ks << 5)));
#pragma unroll
            for (int f = 0; f < 2; ++f) {
                const int dy = m - f;
                if (dy >= 0 && dy < 3) {
#pragma unroll
                    for (int dx = 0; dx < 3; ++dx)
#pragma unroll
                        for (int ks = 0; ks < 2; ++ks)
                            acc[f] = __builtin_amdgcn_mfma_f32_32x32x16_bf16(
                                A[dy][dx][ks], b[dx][ks], acc[f], 0, 0, 0);
                }
            }
        }

        // -- convert + LDS writes for band t+1 --
        if (st) {
            {
                int px0 = (q0 << 2);  // R13 FIX
#pragma unroll
                for (int j = 0; j < 4; ++j) {
                    u32x4 d;
#pragma unroll
                    for (int p = 0; p < 4; ++p) {
                        float a = ok0 ? L0[2 * p][j] : 0.f;
                        float b2 = ok0 ? L0[2 * p + 1][j] : 0.f;
                        d[p] = (unsigned)f2bf(a) | ((unsigned)f2bf(b2) << 16);
                    }
                    *(u32x4*)(wlds + r0s * ROWB + swz(px0 + j, c0)) = d;
                }
            }
            if (kind == 1) {
                int px0 = (q1 << 2);  // R13 FIX
#pragma unroll
                for (int j = 0; j < 4; ++j) {
                    u32x4 d;
#pragma unroll
                    for (int p = 0; p < 4; ++p) {
                        float a = ok1 ? L1[2 * p][j] : 0.f;
                        float b2 = ok1 ? L1[2 * p + 1][j] : 0.f;
                        d[p] = (unsigned)f2bf(a) | ((unsigned)f2bf(b2) << 16);
                    }
                    *(u32x4*)(wlds + r1s * ROWB + swz(px0 + j, c1)) = d;
                }
            } else if (kind == 2) {
                u32x4 d;
#pragma unroll
                for (int p = 0; p < 4; ++p) {
                    float a = okh ? H[2 * p] : 0.f;
                    float b2 = okh ? H[2 * p + 1] : 0.f;
                    d[p] = (unsigned)f2bf(a) | ((unsigned)f2bf(b2) << 16);
                }
                *(u32x4*)(wlds + hr * ROWB + swz(32 + hside, hc)) = d;
            }
        }

        // -- stores --
#pragma unroll
        for (int f = 0; f < 2; ++f) {
            int gy = R + (wv << 1) + f;
#pragma unroll
            for (int reg = 0; reg < 16; ++reg) {
                int o = (reg & 3) + 8 * (reg >> 2) + 4 * kh;
                size_t oidx = ((size_t)(n * 32 + o) << 18) + ((size_t)gy << 9) + x0t + pxl;
                __builtin_nontemporal_store(acc[f][reg], &out[oidx]);
            }
        }
        __syncthreads();
    }
}

extern "C" void kernel_launch(void* const* d_in, const int* in_sizes, int n_in,
                              void* d_out, int out_size, void* d_ws, size_t ws_size,
                              hipStream_t stream) {
    const float* x = (const float*)d_in[0];
    const float* fw = (const float*)d_in[1];
    float* out = (float*)d_out;
    unsigned short* wbuf = (unsigned short*)d_ws;  // 18*1024 bf16 = 36864 B

    prep_kernel<<<dim3(4), 256, 0, stream>>>(fw, wbuf);
    conv_pipe<<<dim3(1024), 256, 0, stream>>>(x, wbuf, out);
}